// Round 4
// baseline (263.674 us; speedup 1.0000x reference)
//
#include <hip/hip_runtime.h>

typedef unsigned short ushort_t;
typedef __attribute__((ext_vector_type(8)))  short  short8;
typedef __attribute__((ext_vector_type(4)))  float  float4v;
typedef __attribute__((ext_vector_type(2)))  int    int2v;

#define N_NODES 4096
#define NHEADS  4
#define DK      128
#define ODIM    512
#define KDIM    512

__device__ __forceinline__ float bf2f(ushort_t u) {
    return __uint_as_float(((unsigned)u) << 16);
}
__device__ __forceinline__ ushort_t f2bf_rne(float f) {
    unsigned u = __float_as_uint(f);
    u += 0x7fffu + ((u >> 16) & 1u);
    return (ushort_t)(u >> 16);
}

// ---------------------------------------------------------------------------
// Kernel 0: input-dtype detector (1 = fp32 inputs).
// ---------------------------------------------------------------------------
__global__ __launch_bounds__(64) void detect_k(const ushort_t* __restrict__ Hraw,
                                               int* __restrict__ flag)
{
    const int lane = threadIdx.x;
    int cnt = 0;
    #pragma unroll
    for (int s = 0; s < 16; ++s) {
        ushort_t v = Hraw[(lane * 16 + s) * 2];
        int e = (v >> 7) & 0xFF;
        cnt += (((e >= 90) && (e <= 140)) || (v == 0)) ? 1 : 0;
    }
    #pragma unroll
    for (int off = 32; off; off >>= 1) cnt += __shfl_down(cnt, off);
    if (lane == 0) *flag = (cnt < 768) ? 1 : 0;
}

// ---------------------------------------------------------------------------
// Kernel 1: bit-pack mask = (A != 0) || (i == j).  64 MB -> 2 MB.
// ---------------------------------------------------------------------------
__global__ __launch_bounds__(256) void pack_mask_k(const int* __restrict__ A,
                                                   unsigned long long* __restrict__ P)
{
    int flat = blockIdx.x * 256 + threadIdx.x;
    int row  = flat >> 12;
    int col  = flat & 4095;
    int a    = A[flat];
    unsigned long long m = __ballot((a != 0) || (row == col));
    if ((threadIdx.x & 63) == 0) P[flat >> 6] = m;
}

// ---------------------------------------------------------------------------
// Kernel 2: WT[n][k] = W[k][n] as bf16 (dual-dtype input).
// ---------------------------------------------------------------------------
__global__ __launch_bounds__(256) void transpose_w_k(const void* __restrict__ W,
                                                     ushort_t* __restrict__ WT,
                                                     const int* __restrict__ flag)
{
    __shared__ ushort_t lt[64][72];
    const int f32 = *flag;
    const int tid = threadIdx.x;
    const int ti = blockIdx.x >> 3, tj = blockIdx.x & 7;
    const int r = tid >> 2, c2 = tid & 3;
    const size_t eo = (size_t)(ti * 64 + r) * KDIM + tj * 64 + c2 * 16;
    if (f32) {
        const float4v* src = (const float4v*)((const float*)W + eo);
        float4v f0 = src[0], f1 = src[1], f2 = src[2], f3 = src[3];
        #pragma unroll
        for (int e = 0; e < 4; ++e) {
            lt[r][c2 * 16 +  0 + e] = f2bf_rne(f0[e]);
            lt[r][c2 * 16 +  4 + e] = f2bf_rne(f1[e]);
            lt[r][c2 * 16 +  8 + e] = f2bf_rne(f2[e]);
            lt[r][c2 * 16 + 12 + e] = f2bf_rne(f3[e]);
        }
    } else {
        const short8* src = (const short8*)((const ushort_t*)W + eo);
        short8 v0 = src[0];
        short8 v1 = src[1];
        *(short8*)&lt[r][c2 * 16]     = v0;
        *(short8*)&lt[r][c2 * 16 + 8] = v1;
    }
    __syncthreads();
    #pragma unroll
    for (int itr = 0; itr < 2; ++itr) {
        int idx = itr * 256 + tid;
        int n = idx >> 3, c = idx & 7;
        short8 vv;
        #pragma unroll
        for (int e = 0; e < 8; ++e) vv[e] = (short)lt[c * 8 + e][n];
        *(short8*)(WT + (size_t)(tj * 64 + n) * KDIM + ti * 64 + c * 8) = vv;
    }
}

// ---------------------------------------------------------------------------
// Kernel 3: WhT[n][i] = (H @ W)[i][n].  16x16x32 MFMA, dual-dtype A loads.
// ---------------------------------------------------------------------------
__global__ __launch_bounds__(256) void gemm_wht_k(const void* __restrict__ H,
                                                  const ushort_t* __restrict__ WT,
                                                  ushort_t* __restrict__ WhT,
                                                  const int* __restrict__ flag)
{
    __shared__ ushort_t lt[64][72];
    const int f32 = *flag;
    const int tid  = threadIdx.x;
    const int lane = tid & 63;
    const int wid  = tid >> 6;
    const int quad = lane >> 4;
    const int l15  = lane & 15;
    const int bm = blockIdx.x >> 3, bn = blockIdx.x & 7;
    const int i0 = bm * 64, n0 = bn * 64;

    const size_t aoff = (size_t)(i0 + wid * 16 + l15) * KDIM + quad * 8;
    const short8* bp0 = (const short8*)(WT + (size_t)(n0 +  0 + l15) * KDIM) + quad;
    const short8* bp1 = (const short8*)(WT + (size_t)(n0 + 16 + l15) * KDIM) + quad;
    const short8* bp2 = (const short8*)(WT + (size_t)(n0 + 32 + l15) * KDIM) + quad;
    const short8* bp3 = (const short8*)(WT + (size_t)(n0 + 48 + l15) * KDIM) + quad;

    float4v acc0, acc1, acc2, acc3;
    #pragma unroll
    for (int e = 0; e < 4; ++e) { acc0[e] = 0.f; acc1[e] = 0.f; acc2[e] = 0.f; acc3[e] = 0.f; }

    #pragma unroll 4
    for (int k8 = 0; k8 < 64; k8 += 4) {
        short8 a;
        if (f32) {
            const float4v* fp = (const float4v*)((const float*)H + aoff + (size_t)k8 * 8);
            float4v x0 = fp[0], x1 = fp[1];
            #pragma unroll
            for (int e = 0; e < 4; ++e) {
                a[e]     = (short)f2bf_rne(x0[e]);
                a[4 + e] = (short)f2bf_rne(x1[e]);
            }
        } else {
            a = *(const short8*)((const ushort_t*)H + aoff + (size_t)k8 * 8);
        }
        acc0 = __builtin_amdgcn_mfma_f32_16x16x32_bf16(a, bp0[k8], acc0, 0, 0, 0);
        acc1 = __builtin_amdgcn_mfma_f32_16x16x32_bf16(a, bp1[k8], acc1, 0, 0, 0);
        acc2 = __builtin_amdgcn_mfma_f32_16x16x32_bf16(a, bp2[k8], acc2, 0, 0, 0);
        acc3 = __builtin_amdgcn_mfma_f32_16x16x32_bf16(a, bp3[k8], acc3, 0, 0, 0);
    }

    #pragma unroll
    for (int r = 0; r < 4; ++r) {
        int m = wid * 16 + quad * 4 + r;
        lt[ 0 + l15][m] = f2bf_rne(acc0[r]);
        lt[16 + l15][m] = f2bf_rne(acc1[r]);
        lt[32 + l15][m] = f2bf_rne(acc2[r]);
        lt[48 + l15][m] = f2bf_rne(acc3[r]);
    }
    __syncthreads();
    #pragma unroll
    for (int itr = 0; itr < 2; ++itr) {
        int idx = itr * 256 + tid;
        int n = idx >> 3, c = idx & 7;
        short8 v = *(const short8*)&lt[n][c * 8];
        *(short8*)(WhT + (size_t)(n0 + n) * N_NODES + i0 + c * 8) = v;
    }
}

// ---------------------------------------------------------------------------
// Kernel 4: sl[h][i], sr[h][i] from WhT (bf16) and a_l/a_r (dual-dtype).
// ---------------------------------------------------------------------------
__global__ __launch_bounds__(256) void slsr_k(const ushort_t* __restrict__ WhT,
                                              const void* __restrict__ al,
                                              const void* __restrict__ ar,
                                              float* __restrict__ sl,
                                              float* __restrict__ sr,
                                              const int* __restrict__ flag)
{
    const int f32 = *flag;
    const int b = blockIdx.x;
    const int h = b >> 4;
    const int i = ((b & 15) << 8) + threadIdx.x;
    float asl = 0.f, asr = 0.f;
    #pragma unroll 8
    for (int d = 0; d < DK; ++d) {
        float v  = bf2f(WhT[(size_t)(h * DK + d) * N_NODES + i]);
        float av = f32 ? ((const float*)al)[h * DK + d] : bf2f(((const ushort_t*)al)[h * DK + d]);
        float bv = f32 ? ((const float*)ar)[h * DK + d] : bf2f(((const ushort_t*)ar)[h * DK + d]);
        asl += v * av;
        asr += v * bv;
    }
    sl[h * N_NODES + i] = asl;
    sr[h * N_NODES + i] = asr;
}

// ---------------------------------------------------------------------------
// Kernel 5 v2: attention.  Block = (64-row i-tile, head), 1024 thr = 16 waves.
// MFMA role: wave = (nt in [0,8), kseg in [0,2)) -> 4 MFMAs/window, acc 16 reg.
// Softmax role: wave = (rg in [0,4), jq in [0,4)) -> distributed, no redundancy;
// P goes through LDS pbuf in verified 16x16x32 A-layout.  V (B-frags) read
// directly from L2-resident WhT, prefetched at iter top (hidden by softmax).
// ---------------------------------------------------------------------------
__global__ __launch_bounds__(1024) void attn_k(const ushort_t* __restrict__ WhT,
                                               const unsigned* __restrict__ Apack,
                                               const float* __restrict__ sl,
                                               const float* __restrict__ sr,
                                               void* __restrict__ out,
                                               const int* __restrict__ flag)
{
    __shared__ float    srs[N_NODES];        // 16 KB
    __shared__ ushort_t pbuf[64][72];        // 9 KB   P window (bf16, A-layout rows)
    __shared__ float    red[64][128];        // 32 KB  kseg reduction (epilogue only)
    __shared__ float    lsum[4][64];         // 1 KB   denom partials

    const int f32  = *flag;
    const int tid  = threadIdx.x;
    const int lane = tid & 63;
    const int wid  = tid >> 6;        // 0..15
    const int quad = lane >> 4;
    const int l15  = lane & 15;
    const int h    = blockIdx.x & 3;
    const int i0   = (blockIdx.x >> 2) << 6;
    // MFMA role
    const int nt   = wid & 7;         // which 16-dim column tile
    const int kseg = wid >> 3;        // which 32-j half of the window
    // softmax role
    const int rg   = wid & 3;         // 16-row group
    const int jq   = wid >> 2;        // 16-j quarter

    for (int j = tid; j < N_NODES; j += 1024) srs[j] = sr[h * N_NODES + j];

    const int   srow = i0 + rg * 16 + l15;
    const float slv  = sl[h * N_NODES + srow];
    const float C1 = 1.44269504f;             // log2(e)
    const float C2 = 0.2f * 1.44269504f;
    const int   bitbase = (jq * 16 + quad * 4) & 31;
    const unsigned* mbase = Apack + (size_t)srow * 128 + (jq >> 1);

    const ushort_t* vbase = WhT + (size_t)(h * DK + nt * 16 + l15) * N_NODES
                          + kseg * 32 + quad * 8;

    float4v acc[4];
    #pragma unroll
    for (int mg = 0; mg < 4; ++mg)
        #pragma unroll
        for (int e = 0; e < 4; ++e) acc[mg][e] = 0.f;
    float lacc = 0.f;

    __syncthreads();                          // srs ready

    for (int it = 0; it < 64; ++it) {
        const int j0 = it << 6;
        // prefetch this window's B-frag from L2 (consumed after barrier)
        short8 bfrag = *(const short8*)(vbase + j0);

        // ---- softmax quarter: 4 elements per lane ----
        float4v srv = *(const float4v*)&srs[j0 + jq * 16 + quad * 4];
        unsigned w  = mbase[it * 2];
        unsigned u01, u23;
        {
            float p[4];
            #pragma unroll
            for (int jj = 0; jj < 4; ++jj) {
                float x = slv + srv[jj];
                float t = fmaxf(x * C1, x * C2);
                t = ((w >> (bitbase + jj)) & 1u) ? t : -1e30f;
                p[jj] = __builtin_amdgcn_exp2f(t);
            }
            u01 = __builtin_amdgcn_perm(__float_as_uint(p[1]), __float_as_uint(p[0]),
                                        0x07060302u);
            u23 = __builtin_amdgcn_perm(__float_as_uint(p[3]), __float_as_uint(p[2]),
                                        0x07060302u);
            lacc += __uint_as_float(u01 << 16);
            lacc += __uint_as_float(u01 & 0xffff0000u);
            lacc += __uint_as_float(u23 << 16);
            lacc += __uint_as_float(u23 & 0xffff0000u);
        }
        int2v pv; pv[0] = (int)u01; pv[1] = (int)u23;
        *(int2v*)&pbuf[rg * 16 + l15][jq * 16 + quad * 4] = pv;

        __syncthreads();                      // pbuf ready

        #pragma unroll
        for (int mg = 0; mg < 4; ++mg) {
            short8 af = *(const short8*)&pbuf[mg * 16 + l15][kseg * 32 + quad * 8];
            acc[mg] = __builtin_amdgcn_mfma_f32_16x16x32_bf16(af, bfrag, acc[mg], 0, 0, 0);
        }

        __syncthreads();                      // pbuf consumed (safe to rewrite)
    }

    // ---- epilogue ----
    lacc += __shfl_xor(lacc, 16);
    lacc += __shfl_xor(lacc, 32);
    if (lane < 16) lsum[jq][rg * 16 + lane] = lacc;

    if (kseg == 1) {
        #pragma unroll
        for (int mg = 0; mg < 4; ++mg)
            #pragma unroll
            for (int r = 0; r < 4; ++r)
                red[mg * 16 + quad * 4 + r][nt * 16 + l15] = acc[mg][r];
    }
    __syncthreads();

    if (kseg == 0) {
        #pragma unroll
        for (int mg = 0; mg < 4; ++mg)
            #pragma unroll
            for (int r = 0; r < 4; ++r) {
                int rowi = mg * 16 + quad * 4 + r;
                float den = lsum[0][rowi] + lsum[1][rowi] + lsum[2][rowi] + lsum[3][rowi];
                float v = (acc[mg][r] + red[rowi][nt * 16 + l15])
                        * (1.0f / fmaxf(den, 1e-37f));
                float e = __builtin_amdgcn_exp2f(v * C1) - 1.0f;
                float o = (v > 0.f) ? v : e;
                size_t oidx = (size_t)(i0 + rowi) * ODIM + h * DK + nt * 16 + l15;
                if (f32) ((float*)out)[oidx] = o;
                else     ((ushort_t*)out)[oidx] = f2bf_rne(o);
            }
    }
}

// ---------------------------------------------------------------------------
extern "C" void kernel_launch(void* const* d_in, const int* in_sizes, int n_in,
                              void* d_out, int out_size, void* d_ws, size_t ws_size,
                              hipStream_t stream)
{
    const void* H  = d_in[0];
    const int*  A  = (const int*)d_in[1];
    const void* W  = d_in[2];
    const void* al = d_in[3];
    const void* ar = d_in[4];

    if (ws_size < (7u << 20)) return;

    char* ws = (char*)d_ws;
    ushort_t* WhT   = (ushort_t*)ws;                                    // 4 MB
    unsigned long long* Apack = (unsigned long long*)(ws + (4u << 20)); // 2 MB
    ushort_t* WT    = (ushort_t*)(ws + (6u << 20));                     // 512 KB
    float*    sl    = (float*)(ws + (6u << 20) + (512u << 10));         // 64 KB
    float*    sr    = (float*)(ws + (6u << 20) + (576u << 10));         // 64 KB
    int*      flag  = (int*)(ws + (6u << 20) + (640u << 10));           // 4 B

    detect_k    <<<1,     64,   0, stream>>>((const ushort_t*)H, flag);
    pack_mask_k <<<65536, 256,  0, stream>>>(A, Apack);
    transpose_w_k<<<64,   256,  0, stream>>>(W, WT, flag);
    gemm_wht_k  <<<512,   256,  0, stream>>>(H, WT, WhT, flag);
    slsr_k      <<<64,    256,  0, stream>>>(WhT, al, ar, sl, sr, flag);
    attn_k      <<<256,   1024, 0, stream>>>(WhT, (const unsigned*)Apack, sl, sr, (void*)d_out, flag);
}

// Round 5
// 236.805 us; speedup vs baseline: 1.1135x; 1.1135x over previous
//
#include <hip/hip_runtime.h>

typedef unsigned short ushort_t;
typedef __attribute__((ext_vector_type(8)))  short  short8;
typedef __attribute__((ext_vector_type(4)))  float  float4v;

#define N_NODES 4096
#define NHEADS  4
#define DK      128
#define ODIM    512
#define KDIM    512

__device__ __forceinline__ float bf2f(ushort_t u) {
    return __uint_as_float(((unsigned)u) << 16);
}
__device__ __forceinline__ ushort_t f2bf_rne(float f) {
    unsigned u = __float_as_uint(f);
    u += 0x7fffu + ((u >> 16) & 1u);
    return (ushort_t)(u >> 16);
}

// ---------------------------------------------------------------------------
// Kernel 0: input-dtype detector (1 = fp32 inputs).
// ---------------------------------------------------------------------------
__global__ __launch_bounds__(64) void detect_k(const ushort_t* __restrict__ Hraw,
                                               int* __restrict__ flag)
{
    const int lane = threadIdx.x;
    int cnt = 0;
    #pragma unroll
    for (int s = 0; s < 16; ++s) {
        ushort_t v = Hraw[(lane * 16 + s) * 2];
        int e = (v >> 7) & 0xFF;
        cnt += (((e >= 90) && (e <= 140)) || (v == 0)) ? 1 : 0;
    }
    #pragma unroll
    for (int off = 32; off; off >>= 1) cnt += __shfl_down(cnt, off);
    if (lane == 0) *flag = (cnt < 768) ? 1 : 0;
}

// ---------------------------------------------------------------------------
// Kernel 1: bit-pack mask = (A != 0) || (i == j).  64 MB -> 2 MB.
// ---------------------------------------------------------------------------
__global__ __launch_bounds__(256) void pack_mask_k(const int* __restrict__ A,
                                                   unsigned long long* __restrict__ P)
{
    int flat = blockIdx.x * 256 + threadIdx.x;
    int row  = flat >> 12;
    int col  = flat & 4095;
    int a    = A[flat];
    unsigned long long m = __ballot((a != 0) || (row == col));
    if ((threadIdx.x & 63) == 0) P[flat >> 6] = m;
}

// ---------------------------------------------------------------------------
// Kernel 1b: H -> bf16 (dual-dtype input), 8 elems/thread.
// ---------------------------------------------------------------------------
__global__ __launch_bounds__(256) void convh_k(const void* __restrict__ H,
                                               ushort_t* __restrict__ Hb,
                                               const int* __restrict__ flag)
{
    const int f32 = *flag;
    const size_t base = ((size_t)blockIdx.x * 256 + threadIdx.x) * 8;
    if (f32) {
        const float4v* s = (const float4v*)((const float*)H + base);
        float4v a = s[0], b = s[1];
        short8 v;
        #pragma unroll
        for (int e = 0; e < 4; ++e) {
            v[e]     = (short)f2bf_rne(a[e]);
            v[4 + e] = (short)f2bf_rne(b[e]);
        }
        *(short8*)(Hb + base) = v;
    } else {
        *(short8*)(Hb + base) = *(const short8*)((const ushort_t*)H + base);
    }
}

// ---------------------------------------------------------------------------
// Kernel 2: WT[n][k] = W[k][n] as bf16 (dual-dtype input).
// ---------------------------------------------------------------------------
__global__ __launch_bounds__(256) void transpose_w_k(const void* __restrict__ W,
                                                     ushort_t* __restrict__ WT,
                                                     const int* __restrict__ flag)
{
    __shared__ ushort_t lt[64][72];
    const int f32 = *flag;
    const int tid = threadIdx.x;
    const int ti = blockIdx.x >> 3, tj = blockIdx.x & 7;
    const int r = tid >> 2, c2 = tid & 3;
    const size_t eo = (size_t)(ti * 64 + r) * KDIM + tj * 64 + c2 * 16;
    if (f32) {
        const float4v* src = (const float4v*)((const float*)W + eo);
        float4v f0 = src[0], f1 = src[1], f2 = src[2], f3 = src[3];
        #pragma unroll
        for (int e = 0; e < 4; ++e) {
            lt[r][c2 * 16 +  0 + e] = f2bf_rne(f0[e]);
            lt[r][c2 * 16 +  4 + e] = f2bf_rne(f1[e]);
            lt[r][c2 * 16 +  8 + e] = f2bf_rne(f2[e]);
            lt[r][c2 * 16 + 12 + e] = f2bf_rne(f3[e]);
        }
    } else {
        const short8* src = (const short8*)((const ushort_t*)W + eo);
        short8 v0 = src[0];
        short8 v1 = src[1];
        *(short8*)&lt[r][c2 * 16]     = v0;
        *(short8*)&lt[r][c2 * 16 + 8] = v1;
    }
    __syncthreads();
    #pragma unroll
    for (int itr = 0; itr < 2; ++itr) {
        int idx = itr * 256 + tid;
        int n = idx >> 3, c = idx & 7;
        short8 vv;
        #pragma unroll
        for (int e = 0; e < 8; ++e) vv[e] = (short)lt[c * 8 + e][n];
        *(short8*)(WT + (size_t)(tj * 64 + n) * KDIM + ti * 64 + c * 8) = vv;
    }
}

// ---------------------------------------------------------------------------
// Kernel 3: WhT[n][i] = (Hb @ W)[i][n].  16x16x32 MFMA, bf16 A direct loads.
// ---------------------------------------------------------------------------
__global__ __launch_bounds__(256) void gemm_wht_k(const ushort_t* __restrict__ Hb,
                                                  const ushort_t* __restrict__ WT,
                                                  ushort_t* __restrict__ WhT)
{
    __shared__ ushort_t lt[64][72];
    const int tid  = threadIdx.x;
    const int lane = tid & 63;
    const int wid  = tid >> 6;
    const int quad = lane >> 4;
    const int l15  = lane & 15;
    const int bm = blockIdx.x >> 3, bn = blockIdx.x & 7;
    const int i0 = bm * 64, n0 = bn * 64;

    const short8* ap  = (const short8*)(Hb + (size_t)(i0 + wid * 16 + l15) * KDIM) + quad;
    const short8* bp0 = (const short8*)(WT + (size_t)(n0 +  0 + l15) * KDIM) + quad;
    const short8* bp1 = (const short8*)(WT + (size_t)(n0 + 16 + l15) * KDIM) + quad;
    const short8* bp2 = (const short8*)(WT + (size_t)(n0 + 32 + l15) * KDIM) + quad;
    const short8* bp3 = (const short8*)(WT + (size_t)(n0 + 48 + l15) * KDIM) + quad;

    float4v acc0, acc1, acc2, acc3;
    #pragma unroll
    for (int e = 0; e < 4; ++e) { acc0[e] = 0.f; acc1[e] = 0.f; acc2[e] = 0.f; acc3[e] = 0.f; }

    #pragma unroll 4
    for (int k8 = 0; k8 < 64; k8 += 4) {
        short8 a = ap[k8];
        acc0 = __builtin_amdgcn_mfma_f32_16x16x32_bf16(a, bp0[k8], acc0, 0, 0, 0);
        acc1 = __builtin_amdgcn_mfma_f32_16x16x32_bf16(a, bp1[k8], acc1, 0, 0, 0);
        acc2 = __builtin_amdgcn_mfma_f32_16x16x32_bf16(a, bp2[k8], acc2, 0, 0, 0);
        acc3 = __builtin_amdgcn_mfma_f32_16x16x32_bf16(a, bp3[k8], acc3, 0, 0, 0);
    }

    #pragma unroll
    for (int r = 0; r < 4; ++r) {
        int m = wid * 16 + quad * 4 + r;
        lt[ 0 + l15][m] = f2bf_rne(acc0[r]);
        lt[16 + l15][m] = f2bf_rne(acc1[r]);
        lt[32 + l15][m] = f2bf_rne(acc2[r]);
        lt[48 + l15][m] = f2bf_rne(acc3[r]);
    }
    __syncthreads();
    #pragma unroll
    for (int itr = 0; itr < 2; ++itr) {
        int idx = itr * 256 + tid;
        int n = idx >> 3, c = idx & 7;
        short8 v = *(const short8*)&lt[n][c * 8];
        *(short8*)(WhT + (size_t)(n0 + n) * N_NODES + i0 + c * 8) = v;
    }
}

// Fallback gemm (dual-dtype H) if ws is too small for Hb.
__global__ __launch_bounds__(256) void gemm_wht_dual_k(const void* __restrict__ H,
                                                       const ushort_t* __restrict__ WT,
                                                       ushort_t* __restrict__ WhT,
                                                       const int* __restrict__ flag)
{
    __shared__ ushort_t lt[64][72];
    const int f32 = *flag;
    const int tid  = threadIdx.x;
    const int lane = tid & 63;
    const int wid  = tid >> 6;
    const int quad = lane >> 4;
    const int l15  = lane & 15;
    const int bm = blockIdx.x >> 3, bn = blockIdx.x & 7;
    const int i0 = bm * 64, n0 = bn * 64;

    const size_t aoff = (size_t)(i0 + wid * 16 + l15) * KDIM + quad * 8;
    const short8* bp0 = (const short8*)(WT + (size_t)(n0 +  0 + l15) * KDIM) + quad;
    const short8* bp1 = (const short8*)(WT + (size_t)(n0 + 16 + l15) * KDIM) + quad;
    const short8* bp2 = (const short8*)(WT + (size_t)(n0 + 32 + l15) * KDIM) + quad;
    const short8* bp3 = (const short8*)(WT + (size_t)(n0 + 48 + l15) * KDIM) + quad;

    float4v acc0, acc1, acc2, acc3;
    #pragma unroll
    for (int e = 0; e < 4; ++e) { acc0[e] = 0.f; acc1[e] = 0.f; acc2[e] = 0.f; acc3[e] = 0.f; }

    #pragma unroll 4
    for (int k8 = 0; k8 < 64; k8 += 4) {
        short8 a;
        if (f32) {
            const float4v* fp = (const float4v*)((const float*)H + aoff + (size_t)k8 * 8);
            float4v x0 = fp[0], x1 = fp[1];
            #pragma unroll
            for (int e = 0; e < 4; ++e) {
                a[e]     = (short)f2bf_rne(x0[e]);
                a[4 + e] = (short)f2bf_rne(x1[e]);
            }
        } else {
            a = *(const short8*)((const ushort_t*)H + aoff + (size_t)k8 * 8);
        }
        acc0 = __builtin_amdgcn_mfma_f32_16x16x32_bf16(a, bp0[k8], acc0, 0, 0, 0);
        acc1 = __builtin_amdgcn_mfma_f32_16x16x32_bf16(a, bp1[k8], acc1, 0, 0, 0);
        acc2 = __builtin_amdgcn_mfma_f32_16x16x32_bf16(a, bp2[k8], acc2, 0, 0, 0);
        acc3 = __builtin_amdgcn_mfma_f32_16x16x32_bf16(a, bp3[k8], acc3, 0, 0, 0);
    }

    #pragma unroll
    for (int r = 0; r < 4; ++r) {
        int m = wid * 16 + quad * 4 + r;
        lt[ 0 + l15][m] = f2bf_rne(acc0[r]);
        lt[16 + l15][m] = f2bf_rne(acc1[r]);
        lt[32 + l15][m] = f2bf_rne(acc2[r]);
        lt[48 + l15][m] = f2bf_rne(acc3[r]);
    }
    __syncthreads();
    #pragma unroll
    for (int itr = 0; itr < 2; ++itr) {
        int idx = itr * 256 + tid;
        int n = idx >> 3, c = idx & 7;
        short8 v = *(const short8*)&lt[n][c * 8];
        *(short8*)(WhT + (size_t)(n0 + n) * N_NODES + i0 + c * 8) = v;
    }
}

// ---------------------------------------------------------------------------
// Kernel 4: sl[h][i], sr[h][i] from WhT (bf16) and a_l/a_r (dual-dtype).
// ---------------------------------------------------------------------------
__global__ __launch_bounds__(256) void slsr_k(const ushort_t* __restrict__ WhT,
                                              const void* __restrict__ al,
                                              const void* __restrict__ ar,
                                              float* __restrict__ sl,
                                              float* __restrict__ sr,
                                              const int* __restrict__ flag)
{
    const int f32 = *flag;
    const int b = blockIdx.x;
    const int h = b >> 4;
    const int i = ((b & 15) << 8) + threadIdx.x;
    float asl = 0.f, asr = 0.f;
    #pragma unroll 8
    for (int d = 0; d < DK; ++d) {
        float v  = bf2f(WhT[(size_t)(h * DK + d) * N_NODES + i]);
        float av = f32 ? ((const float*)al)[h * DK + d] : bf2f(((const ushort_t*)al)[h * DK + d]);
        float bv = f32 ? ((const float*)ar)[h * DK + d] : bf2f(((const ushort_t*)ar)[h * DK + d]);
        asl += v * av;
        asr += v * bv;
    }
    sl[h * N_NODES + i] = asl;
    sr[h * N_NODES + i] = asr;
}

// ---------------------------------------------------------------------------
// Kernel 5 v3: attention, BARRIER-FREE main loop.
// Block = (32-row i-tile, head), 4 waves; wave = one j-quarter (1024 j).
// Wave per iter (64-j window): P for 32 rows (2 A-frags) in registers,
// V B-frags straight from L2 (16x dwordx4), 32 MFMAs.  sr+mask staged to LDS
// once.  Cross-wave merge of numerator/denominator only in epilogue.
// ---------------------------------------------------------------------------
__global__ __launch_bounds__(256, 2) void attn_k(const ushort_t* __restrict__ WhT,
                                                 const unsigned* __restrict__ Apack,
                                                 const float* __restrict__ sl,
                                                 const float* __restrict__ sr,
                                                 void* __restrict__ out,
                                                 const int* __restrict__ flag)
{
    __shared__ float    srs[N_NODES];        // 16 KB  head's sr
    __shared__ unsigned mbuf[32][128];       // 16 KB  mask rows (32 x 4096 bits)
    __shared__ float    red[2][32][128];     // 32 KB  epilogue merge
    __shared__ float    lsum[4][32];         // 512 B  denom partials

    const int f32  = *flag;
    const int tid  = threadIdx.x;
    const int lane = tid & 63;
    const int wq   = tid >> 6;               // j-quarter 0..3
    const int quad = lane >> 4;
    const int l15  = lane & 15;
    const int h    = blockIdx.x & 3;
    const int i0   = (blockIdx.x >> 2) << 5; // 32-row tile

    for (int j = tid; j < N_NODES; j += 256) srs[j] = sr[h * N_NODES + j];
    for (int t = tid; t < 32 * 128; t += 256) {
        int r = t >> 7, c = t & 127;
        mbuf[r][c] = Apack[(size_t)(i0 + r) * 128 + c];
    }
    const float slv0 = sl[h * N_NODES + i0 + l15];
    const float slv1 = sl[h * N_NODES + i0 + 16 + l15];
    __syncthreads();                          // srs+mbuf ready (only loop-ext barrier)

    const float C1 = 1.44269504f;             // log2(e)
    const float C2 = 0.2f * 1.44269504f;

    float4v acc[2][8];
    #pragma unroll
    for (int mg = 0; mg < 2; ++mg)
        #pragma unroll
        for (int nt = 0; nt < 8; ++nt)
            #pragma unroll
            for (int e = 0; e < 4; ++e) acc[mg][nt][e] = 0.f;
    float lacc0 = 0.f, lacc1 = 0.f;

    // B-frag base: lane holds V^T[d = nt*16+l15][j = quad*8 .. +7]
    const ushort_t* vb = WhT + (size_t)(h * DK + l15) * N_NODES + wq * 1024 + quad * 8;

    for (int it = 0; it < 16; ++it) {
        const int jl = it * 64;               // offset within quarter
        const int j0 = wq * 1024 + jl;        // global j base
        const int mc = (j0 >> 5);             // mask dword col

        // V B-frags from L2 — 16 independent dwordx4 (latency covered by softmax)
        short8 bf[8][2];
        #pragma unroll
        for (int nt = 0; nt < 8; ++nt) {
            bf[nt][0] = *(const short8*)(vb + (size_t)nt * 16 * N_NODES + jl);
            bf[nt][1] = *(const short8*)(vb + (size_t)nt * 16 * N_NODES + jl + 32);
        }

        const unsigned w00 = mbuf[l15][mc],      w01 = mbuf[l15][mc + 1];
        const unsigned w10 = mbuf[16 + l15][mc], w11 = mbuf[16 + l15][mc + 1];

        short8 pf0[2], pf1[2];
        #pragma unroll
        for (int s = 0; s < 2; ++s) {
            const float* sp = &srs[j0 + s * 32 + quad * 8];
            const float4v s0 = *(const float4v*)sp;
            const float4v s1 = *(const float4v*)(sp + 4);
            const unsigned wa = s ? w01 : w00;
            const unsigned wb = s ? w11 : w10;
            #pragma unroll
            for (int jj = 0; jj < 8; ++jj) {
                float srj = (jj < 4) ? s0[jj] : s1[jj - 4];
                int bit = quad * 8 + jj;
                float x0 = slv0 + srj;
                float t0 = fmaxf(x0 * C1, x0 * C2);
                t0 = ((wa >> bit) & 1u) ? t0 : -1e30f;
                float p0 = __builtin_amdgcn_exp2f(t0);
                ushort_t h0 = (ushort_t)(__float_as_uint(p0) >> 16);
                lacc0 += bf2f(h0);
                pf0[s][jj] = (short)h0;

                float x1 = slv1 + srj;
                float t1 = fmaxf(x1 * C1, x1 * C2);
                t1 = ((wb >> bit) & 1u) ? t1 : -1e30f;
                float p1 = __builtin_amdgcn_exp2f(t1);
                ushort_t h1 = (ushort_t)(__float_as_uint(p1) >> 16);
                lacc1 += bf2f(h1);
                pf1[s][jj] = (short)h1;
            }
        }

        #pragma unroll
        for (int nt = 0; nt < 8; ++nt) {
            acc[0][nt] = __builtin_amdgcn_mfma_f32_16x16x32_bf16(pf0[0], bf[nt][0], acc[0][nt], 0, 0, 0);
            acc[0][nt] = __builtin_amdgcn_mfma_f32_16x16x32_bf16(pf0[1], bf[nt][1], acc[0][nt], 0, 0, 0);
            acc[1][nt] = __builtin_amdgcn_mfma_f32_16x16x32_bf16(pf1[0], bf[nt][0], acc[1][nt], 0, 0, 0);
            acc[1][nt] = __builtin_amdgcn_mfma_f32_16x16x32_bf16(pf1[1], bf[nt][1], acc[1][nt], 0, 0, 0);
        }
    }

    // ---- epilogue ----
    lacc0 += __shfl_xor(lacc0, 16);
    lacc0 += __shfl_xor(lacc0, 32);
    lacc1 += __shfl_xor(lacc1, 16);
    lacc1 += __shfl_xor(lacc1, 32);
    if (lane < 16) {
        lsum[wq][l15]      = lacc0;
        lsum[wq][16 + l15] = lacc1;
    }
    if (wq >= 2) {
        #pragma unroll
        for (int mg = 0; mg < 2; ++mg)
            #pragma unroll
            for (int nt = 0; nt < 8; ++nt)
                #pragma unroll
                for (int r = 0; r < 4; ++r)
                    red[wq - 2][mg * 16 + quad * 4 + r][nt * 16 + l15] = acc[mg][nt][r];
    }
    __syncthreads();
    if (wq < 2) {
        #pragma unroll
        for (int mg = 0; mg < 2; ++mg)
            #pragma unroll
            for (int nt = 0; nt < 8; ++nt)
                #pragma unroll
                for (int r = 0; r < 4; ++r)
                    acc[mg][nt][r] += red[wq][mg * 16 + quad * 4 + r][nt * 16 + l15];
    }
    __syncthreads();
    if (wq == 1) {
        #pragma unroll
        for (int mg = 0; mg < 2; ++mg)
            #pragma unroll
            for (int nt = 0; nt < 8; ++nt)
                #pragma unroll
                for (int r = 0; r < 4; ++r)
                    red[0][mg * 16 + quad * 4 + r][nt * 16 + l15] = acc[mg][nt][r];
    }
    __syncthreads();
    if (wq == 0) {
        #pragma unroll
        for (int mg = 0; mg < 2; ++mg) {
            float linv[4];
            #pragma unroll
            for (int r = 0; r < 4; ++r) {
                int rowi = mg * 16 + quad * 4 + r;
                float den = lsum[0][rowi] + lsum[1][rowi] + lsum[2][rowi] + lsum[3][rowi];
                linv[r] = 1.0f / fmaxf(den, 1e-37f);
            }
            #pragma unroll
            for (int nt = 0; nt < 8; ++nt)
                #pragma unroll
                for (int r = 0; r < 4; ++r) {
                    int rowi = mg * 16 + quad * 4 + r;
                    float v = (acc[mg][nt][r] + red[0][rowi][nt * 16 + l15]) * linv[r];
                    float e = __builtin_amdgcn_exp2f(v * C1) - 1.0f;
                    float o = (v > 0.f) ? v : e;
                    size_t oidx = (size_t)(i0 + rowi) * ODIM + h * DK + nt * 16 + l15;
                    if (f32) ((float*)out)[oidx] = o;
                    else     ((ushort_t*)out)[oidx] = f2bf_rne(o);
                }
        }
    }
}

// ---------------------------------------------------------------------------
extern "C" void kernel_launch(void* const* d_in, const int* in_sizes, int n_in,
                              void* d_out, int out_size, void* d_ws, size_t ws_size,
                              hipStream_t stream)
{
    const void* H  = d_in[0];
    const int*  A  = (const int*)d_in[1];
    const void* W  = d_in[2];
    const void* al = d_in[3];
    const void* ar = d_in[4];

    if (ws_size < (7u << 20)) return;

    char* ws = (char*)d_ws;
    ushort_t* WhT   = (ushort_t*)ws;                                    // 4 MB
    unsigned long long* Apack = (unsigned long long*)(ws + (4u << 20)); // 2 MB
    ushort_t* WT    = (ushort_t*)(ws + (6u << 20));                     // 512 KB
    float*    sl    = (float*)(ws + (6u << 20) + (512u << 10));         // 64 KB
    float*    sr    = (float*)(ws + (6u << 20) + (576u << 10));         // 64 KB
    int*      flag  = (int*)(ws + (6u << 20) + (640u << 10));           // 4 B
    ushort_t* Hb    = (ushort_t*)(ws + (7u << 20));                     // 4 MB (optional)
    const bool have_hb = ws_size >= (11u << 20);

    detect_k    <<<1,     64,  0, stream>>>((const ushort_t*)H, flag);
    pack_mask_k <<<65536, 256, 0, stream>>>(A, Apack);
    transpose_w_k<<<64,   256, 0, stream>>>(W, WT, flag);
    if (have_hb) {
        convh_k   <<<1024, 256, 0, stream>>>(H, Hb, flag);
        gemm_wht_k<<<512,  256, 0, stream>>>(Hb, WT, WhT);
    } else {
        gemm_wht_dual_k<<<512, 256, 0, stream>>>(H, WT, WhT, flag);
    }
    slsr_k      <<<64,    256, 0, stream>>>(WhT, al, ar, sl, sr, flag);
    attn_k      <<<512,   256, 0, stream>>>(WhT, (const unsigned*)Apack, sl, sr, (void*)d_out, flag);
}